// Round 12
// baseline (329.085 us; speedup 1.0000x reference)
//
#include <hip/hip_runtime.h>

// ---------------------------------------------------------------------------
// MaskedAutoregressiveFlow (RealNVP coupling) fused kernel for gfx950. R12.
// B=16384 rows, F=64, CTX=128, HID=512, L=8 layers, NB=2 hidden blocks.
//
// R12 = R10 orientation (best: 209.5us) restructured against the measured
// wall: MfmaUtil 34.2% == 64/190 cyc/kc -> A-LDS reads (16-wave x16
// amplification + exposed latency) bound the K-loop. Changes:
//  - 512 threads / 8 waves; wave = 2 m-tiles x 2 n-strips (64x64 out):
//    A-LDS traffic per kc halves (x8 amplification); B still read once.
//    At 512 thr the allocator grants 128 VGPRs (R2-proven); fp8 fits:
//    acc 64 + A-pipe 16 + B-pipe 16 + addr ~112.
//  - Split-half LDS h layout: addr(row,c) = row*528 + ((c>>3)&1)*256
//    + ((c>>4)*8 + (c&7)). One aligned ds_read_b128 = A-frags for TWO kc.
//  - K-loop runs over kc-pairs with 1-pair A prefetch and 1-pair B
//    prefetch (8 MFMA per pair cover the LDS/L2 latencies).
//  - G3: 8 waves x 2 n-tiles (shared A-frag); coupling/staging remapped
//    to 512 threads. ctx staged once (layer-invariant).
// ---------------------------------------------------------------------------

typedef float v4f  __attribute__((ext_vector_type(4)));
typedef float v16f __attribute__((ext_vector_type(16)));
typedef unsigned char uchar;
typedef unsigned long long ull;

#define BATCH 16384
#define NF    64
#define NCTX  128
#define NL    8

#define RS     528   // h row stride (bytes); 16-aligned
#define HHALF  256   // byte offset of the k-odd-half within a row
#define AST    176   // abuf row stride; 16-aligned
#define AHALF  80    // abuf half offset (K=160 -> halves of 80)
#define PST    68    // pbuf row stride (floats)

#define WSCALE     16.0f
#define WSCALE_INV 0.0625f

// packed-weight offsets (fp8 elements = bytes)
#define WIN_EPL   (160 * 512)
#define WH_EPB    (512 * 512)
#define WOUT_EPL  (512 * 64)
#define OFF_WIN   ((size_t)0)
#define OFF_WH    ((size_t)(8 * WIN_EPL))
#define OFF_WOUT  (OFF_WH + (size_t)(16 * WH_EPB))
#define TOT_PACK_ELEMS (OFF_WOUT + (size_t)(8 * WOUT_EPL))
#define NEED_WS   (TOT_PACK_ELEMS)

template<bool HI>
__device__ __forceinline__ unsigned int pk2(float a, float b, unsigned int old) {
    return __builtin_amdgcn_cvt_pk_fp8_f32(a, b, old, HI);
}
__device__ __forceinline__ uchar q8(float v) {
    return (uchar)(__builtin_amdgcn_cvt_pk_fp8_f32(v, v, 0u, false) & 0xffu);
}

// ---------------------------------------------------------------------------
// pack: fp32 -> fp8 e4m3 (x16), DESTINATION-ordered. Identical to R10.
// W_in/W_h -> 32x32x16 B-frag order: frag = kc*16 + nt;
//   lane l: k = kc*16 + (l>>5)*8 + j, n = nt*32 + (l&31).
// W_out -> 16x16x32 B-frag order: frag = kc*4 + nt;
//   lane l: k = kc*32 + (l>>4)*8 + j, n = nt*16 + (l&15).
// ---------------------------------------------------------------------------
__global__ void pack_weights_kernel(const float* __restrict__ W_in,
                                    const float* __restrict__ W_h,
                                    const float* __restrict__ W_out,
                                    unsigned char* __restrict__ ws) {
    const int TIN  = 8 * (WIN_EPL / 8);
    const int TH   = 16 * (WH_EPB / 8);
    const int TOUT = 8 * (WOUT_EPL / 8);
    int t = blockIdx.x * blockDim.x + threadIdx.x;
    if (t >= TIN + TH + TOUT) return;
    float v[8];
    if (t < TIN + TH) {
        const float* src; int r;
        if (t < TIN) {
            int i = t / (WIN_EPL / 8); r = t - i * (WIN_EPL / 8);
            src = W_in + (size_t)i * WIN_EPL;
        } else {
            int u = t - TIN; int ij = u >> 15; r = u & 32767;
            src = W_h + (size_t)ij * WH_EPB;
        }
        int frag = r >> 6, lane = r & 63;
        int k0 = (frag >> 4) * 16 + (lane >> 5) * 8;
        int n  = (frag & 15) * 32 + (lane & 31);
#pragma unroll
        for (int j = 0; j < 8; ++j)
            v[j] = src[(size_t)(k0 + j) * 512 + n] * WSCALE;
    } else {
        int u = t - TIN - TH;
        int i = u >> 12, r = u & 4095;
        const float* src = W_out + (size_t)i * WOUT_EPL;
        int frag = r >> 6, lane = r & 63;
        int k0 = (frag >> 2) * 32 + (lane >> 4) * 8;
        int n  = (frag & 3) * 16 + (lane & 15);
#pragma unroll
        for (int j = 0; j < 8; ++j)
            v[j] = src[(size_t)(k0 + j) * 64 + n] * WSCALE;
    }
    uint2 o;
    o.x = pk2<false>(v[0], v[1], 0u);
    o.x = pk2<true >(v[2], v[3], o.x);
    o.y = pk2<false>(v[4], v[5], 0u);
    o.y = pk2<true >(v[6], v[7], o.y);
    *(uint2*)(ws + (size_t)t * 8) = o;
}

__device__ __forceinline__ v16f mfma32(ull a, ull b, v16f c) {
    return __builtin_amdgcn_mfma_f32_32x32x16_fp8_fp8((long)a, (long)b, c, 0, 0, 0);
}
__device__ __forceinline__ v4f mfma16(ull a, ull b, v4f c) {
    return __builtin_amdgcn_mfma_f32_16x16x32_fp8_fp8((long)a, (long)b, c, 0, 0, 0);
}

// ---------------------------------------------------------------------------
// 32x32x16 fp8 stage, 8-wave config: wave wv owns 2 m-tiles x 2 strips
// (s=2wv, 2wv+1). A from split-half LDS via ds_read_b128 (2 kc per read,
// 1-pair prefetch); B from packed global (1-pair prefetch, vmcnt>0).
// ---------------------------------------------------------------------------
template<int KC, bool PACKED>
__device__ __forceinline__ void gemm32(
    const uchar* __restrict__ wpk,
    const float* __restrict__ wraw,    // raw fp32 [K][512] fallback
    const float* __restrict__ bias,
    const uchar* __restrict__ Abuf, int ast, int ahalf,
    uchar* __restrict__ Obuf,
    int wv, int lane)
{
    constexpr int P = KC / 2;
    const int l31 = lane & 31, hl = lane >> 5;
    const int s0 = wv * 2, s1 = s0 + 1;
    v16f acc00, acc01, acc10, acc11;   // [m-tile][strip]
#pragma unroll
    for (int r = 0; r < 16; ++r) {
        acc00[r] = 0.f; acc01[r] = 0.f; acc10[r] = 0.f; acc11[r] = 0.f;
    }
    const uchar* a0p = Abuf + l31 * ast + hl * ahalf;   // rows 0..31
    const uchar* a1p = a0p + 32 * ast;                  // rows 32..63
    const uchar* bp0 = PACKED ? wpk + (size_t)(s0 * 64 + lane) * 8 : (const uchar*)0;
    const uchar* bp1 = PACKED ? wpk + (size_t)(s1 * 64 + lane) * 8 : (const uchar*)0;

    auto lbraw = [&](int s, int kc) -> ull {
        int n  = s * 32 + l31;
        int k0 = kc * 16 + hl * 8;
        unsigned int lo, hi;
        lo = pk2<false>(wraw[(size_t)(k0 + 0) * 512 + n] * WSCALE,
                        wraw[(size_t)(k0 + 1) * 512 + n] * WSCALE, 0u);
        lo = pk2<true >(wraw[(size_t)(k0 + 2) * 512 + n] * WSCALE,
                        wraw[(size_t)(k0 + 3) * 512 + n] * WSCALE, lo);
        hi = pk2<false>(wraw[(size_t)(k0 + 4) * 512 + n] * WSCALE,
                        wraw[(size_t)(k0 + 5) * 512 + n] * WSCALE, 0u);
        hi = pk2<true >(wraw[(size_t)(k0 + 6) * 512 + n] * WSCALE,
                        wraw[(size_t)(k0 + 7) * 512 + n] * WSCALE, hi);
        return ((ull)hi << 32) | (ull)lo;
    };
    auto lB0 = [&](int kc) -> ull {
        if constexpr (PACKED) return *(const ull*)(bp0 + (size_t)kc * 8192);
        else return lbraw(s0, kc);
    };
    auto lB1 = [&](int kc) -> ull {
        if constexpr (PACKED) return *(const ull*)(bp1 + (size_t)kc * 8192);
        else return lbraw(s1, kc);
    };

    ulonglong2 A0 = *(const ulonglong2*)(a0p);
    ulonglong2 A1 = *(const ulonglong2*)(a1p);
    ull c00 = lB0(0), c01 = lB0(1), c10 = lB1(0), c11 = lB1(1);

#pragma unroll 1
    for (int p = 0; p < P; ++p) {
        const int pn = (p + 1 < P) ? p + 1 : p;      // clamped dup, harmless
        ulonglong2 nA0 = *(const ulonglong2*)(a0p + pn * 16);
        ulonglong2 nA1 = *(const ulonglong2*)(a1p + pn * 16);
        ull n00 = lB0(2 * pn),     n01 = lB0(2 * pn + 1);
        ull n10 = lB1(2 * pn),     n11 = lB1(2 * pn + 1);
        acc00 = mfma32(A0.x, c00, acc00);   // kc = 2p
        acc10 = mfma32(A1.x, c00, acc10);
        acc01 = mfma32(A0.x, c10, acc01);
        acc11 = mfma32(A1.x, c10, acc11);
        acc00 = mfma32(A0.y, c01, acc00);   // kc = 2p+1
        acc10 = mfma32(A1.y, c01, acc10);
        acc01 = mfma32(A0.y, c11, acc01);
        acc11 = mfma32(A1.y, c11, acc11);
        A0 = nA0; A1 = nA1;
        c00 = n00; c01 = n01; c10 = n10; c11 = n11;
    }

    // epilogue: col n = s*32+l31; row = (reg&3)+8*(reg>>2)+4*hl (+32 for m1)
#pragma unroll
    for (int sv = 0; sv < 2; ++sv) {
        int s = sv ? s1 : s0;
        int n = s * 32 + l31;
        int nb = ((n >> 3) & 1) * HHALF + ((n >> 4) << 3) + (n & 7);
        float bv = bias[n];
        const v16f& am0 = sv ? acc01 : acc00;
        const v16f& am1 = sv ? acc11 : acc10;
#pragma unroll
        for (int reg = 0; reg < 16; ++reg) {
            int row = (reg & 3) + 8 * (reg >> 2) + 4 * hl;
            float v0 = fmaxf(fmaf(am0[reg], WSCALE_INV, bv), 0.f);
            Obuf[row * RS + nb] = q8(v0);
            float v1 = fmaxf(fmaf(am1[reg], WSCALE_INV, bv), 0.f);
            Obuf[(row + 32) * RS + nb] = q8(v1);
        }
    }
}

// ---------------------------------------------------------------------------
// G3 (16x16x32 fp8): 8 waves x 2 n-tiles sharing one A-frag stream.
// wave wv: mtb = wv>>1, n-tiles (wv&1)*2 and +1. A from split-half LDS.
// ---------------------------------------------------------------------------
template<bool PACKED>
__device__ __forceinline__ void gemm16_out(
    const uchar* __restrict__ wpk,
    const float* __restrict__ wraw,    // raw fp32 W_out [512][64]
    const float* __restrict__ bias,
    const uchar* __restrict__ Abuf,
    float* __restrict__ Pbuf,
    int wv, int lane)
{
    const int quad = lane >> 4, l15 = lane & 15;
    const int mtb = wv >> 1;
    const int nt0 = (wv & 1) * 2, nt1 = nt0 + 1;
    v4f acc0, acc1;
    acc0[0]=acc0[1]=acc0[2]=acc0[3]=0.f;
    acc1[0]=acc1[1]=acc1[2]=acc1[3]=0.f;
    const int row = mtb * 16 + l15;
    // A bytes for kc: c = kc*32 + quad*8 + j -> half = quad&1,
    // pos = (kc*2 + (quad>>1))*8 + j -> base + kc*16
    const uchar* ap = Abuf + row * RS + (quad & 1) * HHALF + (quad >> 1) * 8;
    const uchar* bp0 = PACKED ? wpk + (size_t)(nt0 * 64 + lane) * 8 : (const uchar*)0;
    const uchar* bp1 = PACKED ? wpk + (size_t)(nt1 * 64 + lane) * 8 : (const uchar*)0;
    constexpr int KC = 16;

    auto lbraw = [&](int nt, int kc) -> ull {
        int n  = nt * 16 + l15;
        int k0 = kc * 32 + quad * 8;
        unsigned int lo, hi;
        lo = pk2<false>(wraw[(size_t)(k0 + 0) * 64 + n] * WSCALE,
                        wraw[(size_t)(k0 + 1) * 64 + n] * WSCALE, 0u);
        lo = pk2<true >(wraw[(size_t)(k0 + 2) * 64 + n] * WSCALE,
                        wraw[(size_t)(k0 + 3) * 64 + n] * WSCALE, lo);
        hi = pk2<false>(wraw[(size_t)(k0 + 4) * 64 + n] * WSCALE,
                        wraw[(size_t)(k0 + 5) * 64 + n] * WSCALE, 0u);
        hi = pk2<true >(wraw[(size_t)(k0 + 6) * 64 + n] * WSCALE,
                        wraw[(size_t)(k0 + 7) * 64 + n] * WSCALE, hi);
        return ((ull)hi << 32) | (ull)lo;
    };
    auto lB0 = [&](int kc) -> ull {
        if constexpr (PACKED) return *(const ull*)(bp0 + (size_t)kc * 2048);
        else return lbraw(nt0, kc);
    };
    auto lB1 = [&](int kc) -> ull {
        if constexpr (PACKED) return *(const ull*)(bp1 + (size_t)kc * 2048);
        else return lbraw(nt1, kc);
    };

    ull a = *(const ull*)(ap);
    ull b0 = lB0(0), b1 = lB1(0);
#pragma unroll 1
    for (int kc = 0; kc < KC; ++kc) {
        const int kn = (kc + 1 < KC) ? kc + 1 : kc;
        ull an  = *(const ull*)(ap + kn * 16);
        ull bn0 = lB0(kn), bn1 = lB1(kn);
        acc0 = mfma16(a, b0, acc0);
        acc1 = mfma16(a, b1, acc1);
        a = an; b0 = bn0; b1 = bn1;
    }
    const int n0 = nt0 * 16 + l15, n1 = nt1 * 16 + l15;
    const float bv0 = bias[n0], bv1 = bias[n1];
#pragma unroll
    for (int r = 0; r < 4; ++r) {
        int rw = mtb * 16 + quad * 4 + r;
        Pbuf[rw * PST + n0] = fmaf(acc0[r], WSCALE_INV, bv0);
        Pbuf[rw * PST + n1] = fmaf(acc1[r], WSCALE_INV, bv1);
    }
}

template<bool PACKED>
__global__ __launch_bounds__(512) void flow_kernel(
    const float* __restrict__ inputs,
    const float* __restrict__ ctx,
    const float* __restrict__ W_in,  const float* __restrict__ b_in,
    const float* __restrict__ W_h,   const float* __restrict__ b_h,
    const float* __restrict__ W_out, const float* __restrict__ b_out,
    const int*   __restrict__ perms,
    const uchar* __restrict__ wpk,
    float* __restrict__ out)
{
    __shared__ __align__(16) uchar hbuf0[64 * RS];   // 33,792 B
    __shared__ __align__(16) uchar hbuf1[64 * RS];   // 33,792 B
    __shared__ __align__(16) uchar abuf[64 * AST];   // 11,264 B
    __shared__ __align__(16) float xbuf[64 * NF];    // 16,384 B
    __shared__ int permsh[NF];

    float* pbuf    = (float*)hbuf1;   // p after G3 (G3 reads hbuf0)
    float* scratch = (float*)hbuf0;   // perm scratch (dead after G3)

    const int tid  = threadIdx.x;
    const int wave = tid >> 6;        // 0..7
    const int lane = tid & 63;
    const int trow = tid >> 3;        // 0..63
    const int tq   = tid & 7;         // 0..7
    const int row0 = blockIdx.x * 64;

    // ---- load + clip x tile (1024 float4 / 512 threads = 2 each)
    {
        const float4* in4 = (const float4*)(inputs + (size_t)row0 * NF);
#pragma unroll
        for (int u = 0; u < 2; ++u) {
            float4 v = in4[tid * 2 + u];
            v.x = fminf(fmaxf(v.x, -1.f), 1.f);
            v.y = fminf(fmaxf(v.y, -1.f), 1.f);
            v.z = fminf(fmaxf(v.z, -1.f), 1.f);
            v.w = fminf(fmaxf(v.w, -1.f), 1.f);
            ((float4*)xbuf)[tid * 2 + u] = v;
        }
    }
    // ---- stage ctx ONCE into abuf cols 32..159 (split-half layout)
    {
#pragma unroll
        for (int u = 0; u < 2; ++u) {
            int q = tq + u * 8;                       // ctx chunk 0..15
            const float* crow = ctx + (size_t)(row0 + trow) * NCTX + q * 8;
            float4 f0 = ((const float4*)crow)[0];
            float4 f1 = ((const float4*)crow)[1];
            uint2 ck;
            ck.x = pk2<false>(f0.x, f0.y, 0u);
            ck.x = pk2<true >(f0.z, f0.w, ck.x);
            ck.y = pk2<false>(f1.x, f1.y, 0u);
            ck.y = pk2<true >(f1.z, f1.w, ck.y);
            // abuf col c = 32+q*8+j: half = q&1, pos = (2+(q>>1))*8 + j
            *(uint2*)(abuf + trow * AST + (q & 1) * AHALF + (2 + (q >> 1)) * 8) = ck;
        }
    }
    float ld_acc = 0.f;
    __syncthreads();

#pragma unroll 1
    for (int i = 0; i < NL; ++i) {
        const int par = i & 1;
        const int idp = par ^ 1;

        // ---- stage id cols 0..31 into abuf (split-half; 256 threads)
        if (tid < 256) {
            int trw = tid >> 2, q = tid & 3;          // id chunk 0..3
            const float* xr = xbuf + trw * NF + idp;
            uint2 idv;
            idv.x = pk2<false>(xr[2 * (q * 8 + 0)], xr[2 * (q * 8 + 1)], 0u);
            idv.x = pk2<true >(xr[2 * (q * 8 + 2)], xr[2 * (q * 8 + 3)], idv.x);
            idv.y = pk2<false>(xr[2 * (q * 8 + 4)], xr[2 * (q * 8 + 5)], 0u);
            idv.y = pk2<true >(xr[2 * (q * 8 + 6)], xr[2 * (q * 8 + 7)], idv.y);
            // col c = q*8+j: half = q&1, pos = (q>>1)*8 + j
            *(uint2*)(abuf + trw * AST + (q & 1) * AHALF + ((q >> 1) << 3)) = idv;
        }
        __syncthreads();

        // ---- G0: K=160 (abuf -> hbuf0)
        gemm32<10, PACKED>(
            PACKED ? wpk + OFF_WIN + (size_t)i * WIN_EPL : (const uchar*)0,
            W_in + (size_t)i * WIN_EPL, b_in + i * 512,
            abuf, AST, AHALF, hbuf0, wave, lane);
        __syncthreads();
        // ---- G1 (hbuf0 -> hbuf1)
        gemm32<32, PACKED>(
            PACKED ? wpk + OFF_WH + (size_t)(i * 2 + 0) * WH_EPB : (const uchar*)0,
            W_h + (size_t)(i * 2 + 0) * WH_EPB, b_h + (i * 2 + 0) * 512,
            hbuf0, RS, HHALF, hbuf1, wave, lane);
        __syncthreads();
        // ---- G2 (hbuf1 -> hbuf0)
        gemm32<32, PACKED>(
            PACKED ? wpk + OFF_WH + (size_t)(i * 2 + 1) * WH_EPB : (const uchar*)0,
            W_h + (size_t)(i * 2 + 1) * WH_EPB, b_h + (i * 2 + 1) * 512,
            hbuf1, RS, HHALF, hbuf0, wave, lane);
        __syncthreads();
        // ---- G3: p = h @ W_out + b_out (hbuf0 -> pbuf = hbuf1)
        gemm16_out<PACKED>(
            PACKED ? wpk + OFF_WOUT + (size_t)i * WOUT_EPL : (const uchar*)0,
            W_out + (size_t)i * WOUT_EPL, b_out + i * 64,
            hbuf0, pbuf, wave, lane);
        __syncthreads();

        // ---- coupling: shift = p[:, :32]; scale = sigmoid(p[:,32:]+2)+1e-3
        {
#pragma unroll
            for (int j = 0; j < 4; ++j) {
                int sc = tq * 4 + j;
                float shiftv = pbuf[trow * PST + sc];
                float z = pbuf[trow * PST + 32 + sc] + 2.0f;
                float s = 1.0f / (1.0f + __expf(-z)) + 0.001f;
                int tc = 2 * sc + par;
                xbuf[trow * NF + tc] = xbuf[trow * NF + tc] * s + shiftv;
                ld_acc += __logf(s);
            }
        }
        __syncthreads();

        // ---- permutation: x = x[:, perm[i]]  (scratch = hbuf0, dead)
        if (i < NL - 1) {
#pragma unroll
            for (int u = 0; u < 2; ++u)
                ((float4*)scratch)[tid * 2 + u] = ((float4*)xbuf)[tid * 2 + u];
            if (tid < NF) permsh[tid] = perms[i * NF + tid];
            __syncthreads();
#pragma unroll
            for (int j = 0; j < 8; ++j) {
                int c = tq * 8 + j;
                xbuf[trow * NF + c] = scratch[trow * NF + permsh[c]];
            }
            __syncthreads();
        }
    }

    // ---- outputs: clip(x) then logdet
    {
#pragma unroll
        for (int u = 0; u < 2; ++u) {
            float4 v = ((float4*)xbuf)[tid * 2 + u];
            v.x = fminf(fmaxf(v.x, -1.f), 1.f);
            v.y = fminf(fmaxf(v.y, -1.f), 1.f);
            v.z = fminf(fmaxf(v.z, -1.f), 1.f);
            v.w = fminf(fmaxf(v.w, -1.f), 1.f);
            ((float4*)(out + (size_t)row0 * NF))[tid * 2 + u] = v;
        }
    }
    // reduce 8 partials per row (lanes 8r..8r+7 contiguous in a wave)
    ld_acc += __shfl_down(ld_acc, 1);
    ld_acc += __shfl_down(ld_acc, 2);
    ld_acc += __shfl_down(ld_acc, 4);
    if (tq == 0) out[(size_t)BATCH * NF + row0 + trow] = ld_acc;
}

extern "C" void kernel_launch(void* const* d_in, const int* in_sizes, int n_in,
                              void* d_out, int out_size, void* d_ws, size_t ws_size,
                              hipStream_t stream) {
    const float* inputs  = (const float*)d_in[0];
    const float* context = (const float*)d_in[1];
    const float* W_in    = (const float*)d_in[2];
    const float* b_in    = (const float*)d_in[3];
    const float* W_h     = (const float*)d_in[4];
    const float* b_h     = (const float*)d_in[5];
    const float* W_out   = (const float*)d_in[6];
    const float* b_out   = (const float*)d_in[7];
    const int*   perms   = (const int*)d_in[8];
    float* out = (float*)d_out;

    if (ws_size >= (size_t)NEED_WS) {
        uchar* ws = (uchar*)d_ws;
        const int total_threads = (int)(TOT_PACK_ELEMS / 8);    // 638976
        pack_weights_kernel<<<(total_threads + 255) / 256, 256, 0, stream>>>(
            W_in, W_h, W_out, ws);
        flow_kernel<true><<<256, 512, 0, stream>>>(
            inputs, context, W_in, b_in, W_h, b_h, W_out, b_out, perms, ws, out);
    } else {
        flow_kernel<false><<<256, 512, 0, stream>>>(
            inputs, context, W_in, b_in, W_h, b_h, W_out, b_out, perms,
            (const uchar*)0, out);
    }
}

// Round 13
// 268.574 us; speedup vs baseline: 1.2253x; 1.2253x over previous
//
#include <hip/hip_runtime.h>

// ---------------------------------------------------------------------------
// MaskedAutoregressiveFlow (RealNVP coupling) fused kernel for gfx950. R13.
// B=16384 rows, F=64, CTX=128, HID=512, L=8 layers, NB=2 hidden blocks.
//
// R13 = R10 (best, 209.5us: 1024thr/16 waves, full fp8, D=4 B-pipeline)
//       + R12's split-half LDS layout (b128 A-reads, 2 kc per read)
//       + layer-invariant ctx staged once.
// R12 proved the layout is spill-free (VGPR 88 @128-budget) but lost to
// occupancy (2 waves/SIMD, MfmaUtil 26.7%). R10 proved 16 waves hides the
// latency (46% occ). This is the untested cell: 16 waves + b128 A-path.
// A-LDS instruction time ~halves (the largest non-MFMA term in R10's
// ~190cyc/kc K-loop pace vs 64cyc MFMA).
// LDS h layout: addr(row,c) = row*528 + ((c>>3)&1)*256 + (c>>4)*8 + (c&7).
// Row stride 528B = 132 dwords = 4 mod 32 -> b128 reads of rows 0..31 tile
// all 32 banks (capacity-minimal 4-phase; SQ_LDS_BANK_CONFLICT counts these
// phases but they are full-BW, not waste).
// ---------------------------------------------------------------------------

typedef float v4f  __attribute__((ext_vector_type(4)));
typedef float v16f __attribute__((ext_vector_type(16)));
typedef unsigned char uchar;
typedef unsigned long long ull;

#define BATCH 16384
#define NF    64
#define NCTX  128
#define NL    8

#define RS     528   // h row stride (bytes)
#define HHALF  256   // byte offset of k-odd 8-byte half groups
#define AST    176   // abuf row stride (bytes)
#define AHALF  80    // abuf half offset (K=160)
#define PST    68    // pbuf row stride (floats)

#define WSCALE     16.0f
#define WSCALE_INV 0.0625f

// packed-weight offsets (fp8 elements = bytes)
#define WIN_EPL   (160 * 512)
#define WH_EPB    (512 * 512)
#define WOUT_EPL  (512 * 64)
#define OFF_WIN   ((size_t)0)
#define OFF_WH    ((size_t)(8 * WIN_EPL))
#define OFF_WOUT  (OFF_WH + (size_t)(16 * WH_EPB))
#define TOT_PACK_ELEMS (OFF_WOUT + (size_t)(8 * WOUT_EPL))
#define NEED_WS   (TOT_PACK_ELEMS)

template<bool HI>
__device__ __forceinline__ unsigned int pk2(float a, float b, unsigned int old) {
    return __builtin_amdgcn_cvt_pk_fp8_f32(a, b, old, HI);
}
__device__ __forceinline__ uchar q8(float v) {
    return (uchar)(__builtin_amdgcn_cvt_pk_fp8_f32(v, v, 0u, false) & 0xffu);
}

// ---------------------------------------------------------------------------
// pack: fp32 -> fp8 e4m3 (x16), DESTINATION-ordered (one 8B store/thread).
// W_in/W_h -> 32x32x16 B-frag order: frag = kc*16 + nt;
//   lane l: k = kc*16 + (l>>5)*8 + j, n = nt*32 + (l&31).
// W_out -> 16x16x32 B-frag order: frag = kc*4 + nt;
//   lane l: k = kc*32 + (l>>4)*8 + j, n = nt*16 + (l&15).
// ---------------------------------------------------------------------------
__global__ void pack_weights_kernel(const float* __restrict__ W_in,
                                    const float* __restrict__ W_h,
                                    const float* __restrict__ W_out,
                                    unsigned char* __restrict__ ws) {
    const int TIN  = 8 * (WIN_EPL / 8);
    const int TH   = 16 * (WH_EPB / 8);
    const int TOUT = 8 * (WOUT_EPL / 8);
    int t = blockIdx.x * blockDim.x + threadIdx.x;
    if (t >= TIN + TH + TOUT) return;
    float v[8];
    if (t < TIN + TH) {
        const float* src; int r;
        if (t < TIN) {
            int i = t / (WIN_EPL / 8); r = t - i * (WIN_EPL / 8);
            src = W_in + (size_t)i * WIN_EPL;
        } else {
            int u = t - TIN; int ij = u >> 15; r = u & 32767;
            src = W_h + (size_t)ij * WH_EPB;
        }
        int frag = r >> 6, lane = r & 63;
        int k0 = (frag >> 4) * 16 + (lane >> 5) * 8;
        int n  = (frag & 15) * 32 + (lane & 31);
#pragma unroll
        for (int j = 0; j < 8; ++j)
            v[j] = src[(size_t)(k0 + j) * 512 + n] * WSCALE;
    } else {
        int u = t - TIN - TH;
        int i = u >> 12, r = u & 4095;
        const float* src = W_out + (size_t)i * WOUT_EPL;
        int frag = r >> 6, lane = r & 63;
        int k0 = (frag >> 2) * 32 + (lane >> 4) * 8;
        int n  = (frag & 3) * 16 + (lane & 15);
#pragma unroll
        for (int j = 0; j < 8; ++j)
            v[j] = src[(size_t)(k0 + j) * 64 + n] * WSCALE;
    }
    uint2 o;
    o.x = pk2<false>(v[0], v[1], 0u);
    o.x = pk2<true >(v[2], v[3], o.x);
    o.y = pk2<false>(v[4], v[5], 0u);
    o.y = pk2<true >(v[6], v[7], o.y);
    *(uint2*)(ws + (size_t)t * 8) = o;
}

__device__ __forceinline__ v16f mfma32(ull a, ull b, v16f c) {
    return __builtin_amdgcn_mfma_f32_32x32x16_fp8_fp8((long)a, (long)b, c, 0, 0, 0);
}
__device__ __forceinline__ v4f mfma16(ull a, ull b, v4f c) {
    return __builtin_amdgcn_mfma_f32_16x16x32_fp8_fp8((long)a, (long)b, c, 0, 0, 0);
}

// ---------------------------------------------------------------------------
// 32x32x16 fp8 stage, 16-wave config: wave owns 2 m-tiles x 1 strip (=wave).
// A from split-half LDS via ds_read_b128 (2 kc per read); B from packed
// global with D=4 register pipeline (vmcnt>0 steady state, as R10).
// ---------------------------------------------------------------------------
template<int KC, bool PACKED>
__device__ __forceinline__ void gemm32(
    const uchar* __restrict__ wpk,
    const float* __restrict__ wraw,    // raw fp32 [K][512] fallback
    const float* __restrict__ bias,
    const uchar* __restrict__ Abuf, int ast, int ahalf,
    uchar* __restrict__ Obuf,
    int strip, int lane)
{
    constexpr int P = KC / 2;
    const int l31 = lane & 31, hl = lane >> 5;
    v16f acc0, acc1;
#pragma unroll
    for (int r = 0; r < 16; ++r) { acc0[r] = 0.f; acc1[r] = 0.f; }
    const uchar* a0p = Abuf + l31 * ast + hl * ahalf;   // rows 0..31
    const uchar* a1p = a0p + 32 * ast;                  // rows 32..63
    const uchar* bptr =
        PACKED ? wpk + (size_t)(strip * 64 + lane) * 8 : (const uchar*)0;

    auto loadB = [&](int kc) -> ull {
        if (kc >= KC) kc = KC - 1;          // clamped dup, in-bounds
        if constexpr (PACKED) {
            return *(const ull*)(bptr + (size_t)kc * 8192);  // 16 strips x 512B
        } else {
            int n  = strip * 32 + l31;
            int k0 = kc * 16 + hl * 8;
            unsigned int lo, hi;
            lo = pk2<false>(wraw[(size_t)(k0 + 0) * 512 + n] * WSCALE,
                            wraw[(size_t)(k0 + 1) * 512 + n] * WSCALE, 0u);
            lo = pk2<true >(wraw[(size_t)(k0 + 2) * 512 + n] * WSCALE,
                            wraw[(size_t)(k0 + 3) * 512 + n] * WSCALE, lo);
            hi = pk2<false>(wraw[(size_t)(k0 + 4) * 512 + n] * WSCALE,
                            wraw[(size_t)(k0 + 5) * 512 + n] * WSCALE, 0u);
            hi = pk2<true >(wraw[(size_t)(k0 + 6) * 512 + n] * WSCALE,
                            wraw[(size_t)(k0 + 7) * 512 + n] * WSCALE, hi);
            return ((ull)hi << 32) | (ull)lo;
        }
    };

    ull b0 = loadB(0), b1 = loadB(1), b2 = loadB(2), b3 = loadB(3);
    int p2 = 0;
#pragma unroll 1
    for (; p2 + 1 < P; p2 += 2) {           // 4 kc per iteration
        ulonglong2 Aa0 = *(const ulonglong2*)(a0p + p2 * 16);
        ulonglong2 Aa1 = *(const ulonglong2*)(a1p + p2 * 16);
        acc0 = mfma32(Aa0.x, b0, acc0);
        acc1 = mfma32(Aa1.x, b0, acc1);
        b0 = loadB(2 * p2 + 4);
        acc0 = mfma32(Aa0.y, b1, acc0);
        acc1 = mfma32(Aa1.y, b1, acc1);
        b1 = loadB(2 * p2 + 5);
        ulonglong2 Ab0 = *(const ulonglong2*)(a0p + p2 * 16 + 16);
        ulonglong2 Ab1 = *(const ulonglong2*)(a1p + p2 * 16 + 16);
        acc0 = mfma32(Ab0.x, b2, acc0);
        acc1 = mfma32(Ab1.x, b2, acc1);
        b2 = loadB(2 * p2 + 6);
        acc0 = mfma32(Ab0.y, b3, acc0);
        acc1 = mfma32(Ab1.y, b3, acc1);
        b3 = loadB(2 * p2 + 7);
    }
    if constexpr (P & 1) {                  // last pair sits in b0,b1
        ulonglong2 Aa0 = *(const ulonglong2*)(a0p + (P - 1) * 16);
        ulonglong2 Aa1 = *(const ulonglong2*)(a1p + (P - 1) * 16);
        acc0 = mfma32(Aa0.x, b0, acc0);
        acc1 = mfma32(Aa1.x, b0, acc1);
        acc0 = mfma32(Aa0.y, b1, acc0);
        acc1 = mfma32(Aa1.y, b1, acc1);
    }

    // epilogue: col n = strip*32+l31; row = (reg&3)+8*(reg>>2)+4*hl (+32)
    const int n = strip * 32 + l31;
    const int nb = ((n >> 3) & 1) * HHALF + ((n >> 4) << 3) + (n & 7);
    const float bv = bias[n];
#pragma unroll
    for (int reg = 0; reg < 16; ++reg) {
        int row = (reg & 3) + 8 * (reg >> 2) + 4 * hl;
        float v0 = fmaxf(fmaf(acc0[reg], WSCALE_INV, bv), 0.f);
        Obuf[row * RS + nb] = q8(v0);
        float v1 = fmaxf(fmaf(acc1[reg], WSCALE_INV, bv), 0.f);
        Obuf[(row + 32) * RS + nb] = q8(v1);
    }
}

// ---------------------------------------------------------------------------
// G3 (16x16x32 fp8), 16-wave: mtb = wave>>2, ntb = wave&3. A from split-half
// LDS (b64 per kc); D=4 B pipeline. fp32 out to pbuf.
// ---------------------------------------------------------------------------
template<bool PACKED>
__device__ __forceinline__ void gemm16_out(
    const uchar* __restrict__ wpk,
    const float* __restrict__ wraw,    // raw fp32 W_out [512][64]
    const float* __restrict__ bias,
    const uchar* __restrict__ Abuf,
    float* __restrict__ Pbuf,
    int mtb, int ntb, int lane)
{
    const int quad = lane >> 4, l15 = lane & 15;
    v4f acc; acc[0] = acc[1] = acc[2] = acc[3] = 0.f;
    const int row = mtb * 16 + l15;
    // c = kc*32 + quad*8 + j -> half = quad&1, pos = (kc*2 + (quad>>1))*8 + j
    const uchar* ap = Abuf + row * RS + (quad & 1) * HHALF + ((quad >> 1) << 3);
    const uchar* bptr =
        PACKED ? wpk + (size_t)(ntb * 64 + lane) * 8 : (const uchar*)0;
    constexpr int KC = 16;

    auto loadB = [&](int kc) -> ull {
        if (kc >= KC) kc = KC - 1;
        if constexpr (PACKED) {
            return *(const ull*)(bptr + (size_t)kc * 2048);   // 4 frags x 512B
        } else {
            int n  = ntb * 16 + l15;
            int k0 = kc * 32 + quad * 8;
            unsigned int lo, hi;
            lo = pk2<false>(wraw[(size_t)(k0 + 0) * 64 + n] * WSCALE,
                            wraw[(size_t)(k0 + 1) * 64 + n] * WSCALE, 0u);
            lo = pk2<true >(wraw[(size_t)(k0 + 2) * 64 + n] * WSCALE,
                            wraw[(size_t)(k0 + 3) * 64 + n] * WSCALE, lo);
            hi = pk2<false>(wraw[(size_t)(k0 + 4) * 64 + n] * WSCALE,
                            wraw[(size_t)(k0 + 5) * 64 + n] * WSCALE, 0u);
            hi = pk2<true >(wraw[(size_t)(k0 + 6) * 64 + n] * WSCALE,
                            wraw[(size_t)(k0 + 7) * 64 + n] * WSCALE, hi);
            return ((ull)hi << 32) | (ull)lo;
        }
    };
    auto step = [&](int kc, ull bb) {
        ull a = *(const ull*)(ap + kc * 16);
        acc = mfma16(a, bb, acc);
    };

    ull b0 = loadB(0), b1 = loadB(1), b2 = loadB(2), b3 = loadB(3);
    int kc = 0;
#pragma unroll 1
    for (; kc + 3 < KC; kc += 4) {
        step(kc + 0, b0); b0 = loadB(kc + 4);
        step(kc + 1, b1); b1 = loadB(kc + 5);
        step(kc + 2, b2); b2 = loadB(kc + 6);
        step(kc + 3, b3); b3 = loadB(kc + 7);
    }

    const int n = ntb * 16 + l15;
    const float bv = bias[n];
#pragma unroll
    for (int r = 0; r < 4; ++r)
        Pbuf[(mtb * 16 + quad * 4 + r) * PST + n] = fmaf(acc[r], WSCALE_INV, bv);
}

template<bool PACKED>
__global__ __launch_bounds__(1024) void flow_kernel(
    const float* __restrict__ inputs,
    const float* __restrict__ ctx,
    const float* __restrict__ W_in,  const float* __restrict__ b_in,
    const float* __restrict__ W_h,   const float* __restrict__ b_h,
    const float* __restrict__ W_out, const float* __restrict__ b_out,
    const int*   __restrict__ perms,
    const uchar* __restrict__ wpk,
    float* __restrict__ out)
{
    __shared__ __align__(16) uchar hbuf0[64 * RS];   // 33,792 B
    __shared__ __align__(16) uchar hbuf1[64 * RS];   // 33,792 B
    __shared__ __align__(16) uchar abuf[64 * AST];   // 11,264 B
    __shared__ __align__(16) float xbuf[64 * NF];    // 16,384 B
    __shared__ int permsh[NF];

    float* pbuf    = (float*)hbuf1;   // p after G3 (G3 reads hbuf0)
    float* scratch = (float*)hbuf0;   // perm scratch (dead after G3)

    const int tid  = threadIdx.x;
    const int wave = tid >> 6;        // 0..15
    const int lane = tid & 63;
    const int trow = tid >> 4;        // 0..63
    const int tq   = tid & 15;        // 0..15
    const int row0 = blockIdx.x * 64;

    // ---- load + clip x tile (1 float4 per thread)
    {
        float4 v = ((const float4*)(inputs + (size_t)row0 * NF))[tid];
        v.x = fminf(fmaxf(v.x, -1.f), 1.f);
        v.y = fminf(fmaxf(v.y, -1.f), 1.f);
        v.z = fminf(fmaxf(v.z, -1.f), 1.f);
        v.w = fminf(fmaxf(v.w, -1.f), 1.f);
        ((float4*)xbuf)[tid] = v;
    }
    // ---- stage ctx ONCE into abuf cols 32..159 (split-half layout)
    {
        const float* crow = ctx + (size_t)(row0 + trow) * NCTX + tq * 8;
        float4 f0 = ((const float4*)crow)[0];
        float4 f1 = ((const float4*)crow)[1];
        uint2 ck;
        ck.x = pk2<false>(f0.x, f0.y, 0u);
        ck.x = pk2<true >(f0.z, f0.w, ck.x);
        ck.y = pk2<false>(f1.x, f1.y, 0u);
        ck.y = pk2<true >(f1.z, f1.w, ck.y);
        // col c = 32+tq*8+j: half = tq&1, pos = (2+(tq>>1))*8 + j
        *(uint2*)(abuf + trow * AST + (tq & 1) * AHALF + (2 + (tq >> 1)) * 8) = ck;
    }
    float ld_acc = 0.f;
    __syncthreads();

#pragma unroll 1
    for (int i = 0; i < NL; ++i) {
        const int par = i & 1;
        const int idp = par ^ 1;

        // ---- stage id cols 0..31 into abuf (split-half)
        if (tq < 4) {
            const float* xr = xbuf + trow * NF + idp;
            uint2 idv;
            idv.x = pk2<false>(xr[2 * (tq * 8 + 0)], xr[2 * (tq * 8 + 1)], 0u);
            idv.x = pk2<true >(xr[2 * (tq * 8 + 2)], xr[2 * (tq * 8 + 3)], idv.x);
            idv.y = pk2<false>(xr[2 * (tq * 8 + 4)], xr[2 * (tq * 8 + 5)], 0u);
            idv.y = pk2<true >(xr[2 * (tq * 8 + 6)], xr[2 * (tq * 8 + 7)], idv.y);
            // col c = tq*8+j: half = tq&1, pos = (tq>>1)*8 + j
            *(uint2*)(abuf + trow * AST + (tq & 1) * AHALF + ((tq >> 1) << 3)) = idv;
        }
        __syncthreads();

        // ---- G0: K=160 (abuf -> hbuf0)
        gemm32<10, PACKED>(
            PACKED ? wpk + OFF_WIN + (size_t)i * WIN_EPL : (const uchar*)0,
            W_in + (size_t)i * WIN_EPL, b_in + i * 512,
            abuf, AST, AHALF, hbuf0, wave, lane);
        __syncthreads();
        // ---- G1 (hbuf0 -> hbuf1)
        gemm32<32, PACKED>(
            PACKED ? wpk + OFF_WH + (size_t)(i * 2 + 0) * WH_EPB : (const uchar*)0,
            W_h + (size_t)(i * 2 + 0) * WH_EPB, b_h + (i * 2 + 0) * 512,
            hbuf0, RS, HHALF, hbuf1, wave, lane);
        __syncthreads();
        // ---- G2 (hbuf1 -> hbuf0)
        gemm32<32, PACKED>(
            PACKED ? wpk + OFF_WH + (size_t)(i * 2 + 1) * WH_EPB : (const uchar*)0,
            W_h + (size_t)(i * 2 + 1) * WH_EPB, b_h + (i * 2 + 1) * 512,
            hbuf1, RS, HHALF, hbuf0, wave, lane);
        __syncthreads();
        // ---- G3: p = h @ W_out + b_out (hbuf0 -> pbuf = hbuf1)
        gemm16_out<PACKED>(
            PACKED ? wpk + OFF_WOUT + (size_t)i * WOUT_EPL : (const uchar*)0,
            W_out + (size_t)i * WOUT_EPL, b_out + i * 64,
            hbuf0, pbuf, wave >> 2, wave & 3, lane);
        __syncthreads();

        // ---- coupling: shift = p[:, :32]; scale = sigmoid(p[:,32:]+2)+1e-3
        {
#pragma unroll
            for (int j = 0; j < 2; ++j) {
                int sc = tq * 2 + j;
                float shiftv = pbuf[trow * PST + sc];
                float z = pbuf[trow * PST + 32 + sc] + 2.0f;
                float s = 1.0f / (1.0f + __expf(-z)) + 0.001f;
                int tc = 2 * sc + par;
                xbuf[trow * NF + tc] = xbuf[trow * NF + tc] * s + shiftv;
                ld_acc += __logf(s);
            }
        }
        __syncthreads();

        // ---- permutation: x = x[:, perm[i]]  (scratch = hbuf0, dead)
        if (i < NL - 1) {
            ((float4*)scratch)[tid] = ((float4*)xbuf)[tid];
            if (tid < NF) permsh[tid] = perms[i * NF + tid];
            __syncthreads();
#pragma unroll
            for (int j = 0; j < 4; ++j) {
                int c = tq * 4 + j;
                xbuf[trow * NF + c] = scratch[trow * NF + permsh[c]];
            }
            __syncthreads();
        }
    }

    // ---- outputs: clip(x) then logdet
    {
        float4 v = ((float4*)xbuf)[tid];
        v.x = fminf(fmaxf(v.x, -1.f), 1.f);
        v.y = fminf(fmaxf(v.y, -1.f), 1.f);
        v.z = fminf(fmaxf(v.z, -1.f), 1.f);
        v.w = fminf(fmaxf(v.w, -1.f), 1.f);
        ((float4*)(out + (size_t)row0 * NF))[tid] = v;
    }
    // reduce 16 partials per row (lanes 16r..16r+15 contiguous in a wave)
    ld_acc += __shfl_down(ld_acc, 1);
    ld_acc += __shfl_down(ld_acc, 2);
    ld_acc += __shfl_down(ld_acc, 4);
    ld_acc += __shfl_down(ld_acc, 8);
    if (tq == 0) out[(size_t)BATCH * NF + row0 + trow] = ld_acc;
}

extern "C" void kernel_launch(void* const* d_in, const int* in_sizes, int n_in,
                              void* d_out, int out_size, void* d_ws, size_t ws_size,
                              hipStream_t stream) {
    const float* inputs  = (const float*)d_in[0];
    const float* context = (const float*)d_in[1];
    const float* W_in    = (const float*)d_in[2];
    const float* b_in    = (const float*)d_in[3];
    const float* W_h     = (const float*)d_in[4];
    const float* b_h     = (const float*)d_in[5];
    const float* W_out   = (const float*)d_in[6];
    const float* b_out   = (const float*)d_in[7];
    const int*   perms   = (const int*)d_in[8];
    float* out = (float*)d_out;

    if (ws_size >= (size_t)NEED_WS) {
        uchar* ws = (uchar*)d_ws;
        const int total_threads = (int)(TOT_PACK_ELEMS / 8);    // 638976
        pack_weights_kernel<<<(total_threads + 255) / 256, 256, 0, stream>>>(
            W_in, W_h, W_out, ws);
        flow_kernel<true><<<256, 1024, 0, stream>>>(
            inputs, context, W_in, b_in, W_h, b_h, W_out, b_out, perms, ws, out);
    } else {
        flow_kernel<false><<<256, 1024, 0, stream>>>(
            inputs, context, W_in, b_in, W_h, b_h, W_out, b_out, perms,
            (const uchar*)0, out);
    }
}